// Round 2
// baseline (11377.379 us; speedup 1.0000x reference)
//
#include <hip/hip_runtime.h>
#include <hip/hip_bf16.h>
#include <cstdint>
#include <cstddef>

typedef __hip_bfloat16 bf16;
typedef __attribute__((ext_vector_type(8))) short short8;
typedef __attribute__((ext_vector_type(4))) float f32x4;

struct __align__(8) bf16x4_s { bf16 x, y, z, w; };

#define N_OBS 72000
#define NB 9000
#define MPAD 72064   /* 563*128 */
#define MT 563
#define PITCH 264    /* bf16 elems; 264/8=33 odd -> even LDS bank spread; rows 16B aligned */
#define VT_PITCH 56  /* vT row: 48 tokens + pad; 112B rows, 16B aligned */

__device__ __forceinline__ float gelu_tanh(float x) {
    const float c = 0.7978845608028654f;
    float x3 = x * x * x;
    return 0.5f * x * (1.0f + tanhf(c * (x + 0.044715f * x3)));
}

// ---------------- slot assignment (permutation-invariant scatter) ----------------
__global__ void slot_kernel(const int* __restrict__ li, int* __restrict__ cnt,
                            int* __restrict__ dst) {
    int i = blockIdx.x * 256 + threadIdx.x;
    if (i >= N_OBS) return;
    int d = li[i * 3], h = li[i * 3 + 1], w = li[i * 3 + 2];
    int flat = d * 1800 + h * 60 + w;
    int slot = atomicAdd(&cnt[flat], 1);
    dst[i] = flat * 8 + slot;
}

// ---------------- weight fp32 [B,K,N] -> bf16 [B,N,K] (row-major Bt) ----------------
__global__ void wtrans(const float* __restrict__ W, bf16* __restrict__ Wt,
                       int K, int N) {
    size_t off = (size_t)blockIdx.y * K * N;
    int idx = blockIdx.x * 256 + threadIdx.x;
    if (idx >= K * N) return;
    int k = idx / N, n = idx % N;
    Wt[off + (size_t)n * K + k] = __float2bfloat16(W[off + idx]);
}

// ---------------- weight fp32 [B,K,N] -> bf16 MFMA-B-fragment-packed ----------------
// P[((nb*(K/32)+kb)*64 + qq*16 + m16)*8 + i], n = nb*16+m16, k = kb*32+qq*8+i
__global__ void pack_b(const float* __restrict__ W, bf16* __restrict__ P,
                       int K, int N) {
    size_t off = (size_t)blockIdx.y * K * N;
    int idx = blockIdx.x * 256 + threadIdx.x;
    if (idx >= K * N) return;
    int k = idx / N, n = idx % N;
    size_t dst = ((((size_t)(n >> 4) * (K >> 5) + (k >> 5)) * 64)
                  + ((k >> 3) & 3) * 16 + (n & 15)) * 8 + (k & 7);
    P[off + dst] = __float2bfloat16(W[off + idx]);
}

// ---------------- x fp32 -> bf16 padded ----------------
__global__ void convx(const float* __restrict__ X, bf16* __restrict__ Y) {
    size_t base = ((size_t)blockIdx.x * 256 + threadIdx.x) * 4;
    size_t row = base >> 8;
    bf16 z = __float2bfloat16(0.0f);
    bf16x4_s o = {z, z, z, z};
    if (row < N_OBS) {
        float4 v = *(const float4*)(X + base);
        o.x = __float2bfloat16(v.x); o.y = __float2bfloat16(v.y);
        o.z = __float2bfloat16(v.z); o.w = __float2bfloat16(v.w);
    }
    *(bf16x4_s*)(Y + base) = o;
}

// ---------------- MFMA GEMM: C[M,N] = act(A[M,K] @ Bt[N,K]^T + bias) ----------------
// MODE: 0 = bf16 out, 2 = fp32 out rows<Mstore, 3 = bf16 A-frag-packed scatter out
template <bool GELU, int MODE>
__global__ __launch_bounds__(256, 2) void gemm_bt(
    const bf16* __restrict__ A, int lda,
    const bf16* __restrict__ Bt, int ldb,
    const float* __restrict__ bias,
    bf16* __restrict__ Cb, float* __restrict__ Cf, int ldc,
    const int* __restrict__ scatter, int scatterN,
    int K, int Mstore) {
    __shared__ __align__(16) bf16 As[128 * 40];
    __shared__ __align__(16) bf16 Bs[128 * 40];
    const int tid = threadIdx.x;
    const int m0 = blockIdx.x * 128;
    const int n0 = blockIdx.y * 128;
    const int wave = tid >> 6, lane = tid & 63;
    const int wm = (wave & 1) * 64, wn = (wave >> 1) * 64;
    const int m16 = lane & 15, qq = lane >> 4;

    f32x4 acc[4][4];
    #pragma unroll
    for (int i = 0; i < 4; i++)
        #pragma unroll
        for (int j = 0; j < 4; j++)
            acc[i][j] = {0.0f, 0.0f, 0.0f, 0.0f};

    const int lrow = tid >> 2;
    const int lq = (tid & 3) * 8;

    for (int k0 = 0; k0 < K; k0 += 32) {
        const uint4 av0 = *(const uint4*)(A + (size_t)(m0 + lrow) * lda + k0 + lq);
        const uint4 av1 = *(const uint4*)(A + (size_t)(m0 + lrow + 64) * lda + k0 + lq);
        const uint4 bv0 = *(const uint4*)(Bt + (size_t)(n0 + lrow) * ldb + k0 + lq);
        const uint4 bv1 = *(const uint4*)(Bt + (size_t)(n0 + lrow + 64) * ldb + k0 + lq);
        *(uint4*)(As + lrow * 40 + lq) = av0;
        *(uint4*)(As + (lrow + 64) * 40 + lq) = av1;
        *(uint4*)(Bs + lrow * 40 + lq) = bv0;
        *(uint4*)(Bs + (lrow + 64) * 40 + lq) = bv1;
        __syncthreads();
        short8 a[4], b[4];
        #pragma unroll
        for (int i = 0; i < 4; i++)
            a[i] = *(const short8*)(As + (wm + i * 16 + m16) * 40 + qq * 8);
        #pragma unroll
        for (int j = 0; j < 4; j++)
            b[j] = *(const short8*)(Bs + (wn + j * 16 + m16) * 40 + qq * 8);
        #pragma unroll
        for (int i = 0; i < 4; i++)
            #pragma unroll
            for (int j = 0; j < 4; j++)
                acc[i][j] = __builtin_amdgcn_mfma_f32_16x16x32_bf16(a[i], b[j], acc[i][j], 0, 0, 0);
        __syncthreads();
    }

    #pragma unroll
    for (int i = 0; i < 4; i++) {
        #pragma unroll
        for (int j = 0; j < 4; j++) {
            const int col = n0 + wn + j * 16 + m16;
            const float bs = bias ? bias[col] : 0.0f;
            #pragma unroll
            for (int r = 0; r < 4; r++) {
                int row = m0 + wm + i * 16 + qq * 4 + r;
                float v = acc[i][j][r] + bs;
                if (GELU) v = gelu_tanh(v);
                if (MODE == 0) {
                    Cb[(size_t)row * ldc + col] = __float2bfloat16(v);
                } else if (MODE == 2) {
                    if (row < Mstore) Cf[(size_t)row * ldc + col] = v;
                } else if (MODE == 3) {
                    if (row < scatterN) {
                        int orow = scatter[row];
                        size_t off = (((size_t)(orow >> 4) * 8 + (col >> 5)) * 64
                                      + ((col >> 3) & 3) * 16 + (orow & 15)) * 8 + (col & 7);
                        Cb[off] = __float2bfloat16(v);
                    }
                }
            }
        }
    }
}

// ================= fused 8-layer cross-attention transformer =================
// block = 384 thr = 6 waves; 6 buckets (48 rows); wave (rb,ch): rows 16rb..+15, cols 128ch..+127
__global__ __launch_bounds__(384, 3) void fused_tr(
    const bf16* __restrict__ ctxp,
    const bf16* __restrict__ Wqp, const bf16* __restrict__ Wkp,
    const bf16* __restrict__ Wvp, const bf16* __restrict__ Wop,
    const bf16* __restrict__ W1p, const bf16* __restrict__ W2p,
    const float* __restrict__ bg,
    const float* __restrict__ ln1g, const float* __restrict__ ln1b,
    const float* __restrict__ bqp, const float* __restrict__ bkp,
    const float* __restrict__ bvp, const float* __restrict__ bop,
    const float* __restrict__ ln2g, const float* __restrict__ ln2b,
    const float* __restrict__ b1p, const float* __restrict__ b2p,
    bf16* __restrict__ trb)
{
    __shared__ __align__(16) bf16 ybuf[48 * PITCH];        // 25344 B
    __shared__ __align__(16) bf16 kbuf[256 * VT_PITCH];    // 28672 B (k row-major / vT / h)
    __shared__ float2 lnred[2][48];                        // 768 B

    const int tid = threadIdx.x;
    const int wave = tid >> 6, lane = tid & 63;
    const int m16 = lane & 15, qq = lane >> 4;
    const int ch = (wave >= 3) ? 1 : 0;
    const int rb = wave - 3 * ch;
    const int R0 = rb * 16;
    const size_t gmb = (size_t)blockIdx.x * 3 + rb;

    f32x4 tr[8];
    #pragma unroll
    for (int j = 0; j < 8; j++) {
        int col = 128 * ch + 16 * j + m16;
        #pragma unroll
        for (int r = 0; r < 4; r++)
            tr[j][r] = bg[((qq * 4 + r) & 7) * 256 + col];
    }

    auto layernorm_to_ybuf = [&](const float* g, const float* b) {
        float s[4] = {0, 0, 0, 0}, s2[4] = {0, 0, 0, 0};
        #pragma unroll
        for (int j = 0; j < 8; j++)
            #pragma unroll
            for (int r = 0; r < 4; r++) { float v = tr[j][r]; s[r] += v; s2[r] += v * v; }
        #pragma unroll
        for (int m = 1; m < 16; m <<= 1)
            #pragma unroll
            for (int r = 0; r < 4; r++) {
                s[r] += __shfl_xor(s[r], m, 64);
                s2[r] += __shfl_xor(s2[r], m, 64);
            }
        if (m16 == 0) {
            #pragma unroll
            for (int r = 0; r < 4; r++)
                lnred[ch][R0 + qq * 4 + r] = make_float2(s[r], s2[r]);
        }
        __syncthreads();
        float mean[4], rstd[4];
        #pragma unroll
        for (int r = 0; r < 4; r++) {
            float2 a = lnred[0][R0 + qq * 4 + r], bb = lnred[1][R0 + qq * 4 + r];
            float su = a.x + bb.x, sq = a.y + bb.y;
            mean[r] = su * (1.0f / 256.0f);
            rstd[r] = rsqrtf(sq * (1.0f / 256.0f) - mean[r] * mean[r] + 1e-5f);
        }
        #pragma unroll
        for (int j = 0; j < 8; j++) {
            int col = 128 * ch + 16 * j + m16;
            float gv = g[col], bv2 = b[col];
            #pragma unroll
            for (int r = 0; r < 4; r++) {
                float y = (tr[j][r] - mean[r]) * rstd[r] * gv + bv2;
                ybuf[(R0 + qq * 4 + r) * PITCH + col] = __float2bfloat16(y);
            }
        }
        __syncthreads();
    };

    auto initb = [&](const float* bias, f32x4* acc) {
        #pragma unroll
        for (int j = 0; j < 8; j++) {
            float bv2 = bias[128 * ch + 16 * j + m16];
            acc[j] = {bv2, bv2, bv2, bv2};
        }
    };
    // A from LDS (rows R0..R0+15, k-cols t*32+qq*8), B frag-packed global
    auto gemm_lds = [&](const bf16* Abuf, const bf16* Wp, int KB, int nbase, int kbB0,
                        f32x4* acc) {
        for (int t = 0; t < 8; t++) {
            short8 a = *(const short8*)(Abuf + (R0 + m16) * PITCH + t * 32 + qq * 8);
            #pragma unroll
            for (int j = 0; j < 8; j++) {
                short8 b = *(const short8*)(Wp + (((size_t)(nbase + j) * KB + kbB0 + t) * 64 + lane) * 8);
                acc[j] = __builtin_amdgcn_mfma_f32_16x16x32_bf16(a, b, acc[j], 0, 0, 0);
            }
        }
    };
    // A = ctx frag-packed global
    auto gemm_ctx = [&](const bf16* Wp, f32x4* acc) {
        for (int t = 0; t < 8; t++) {
            short8 a = *(const short8*)(ctxp + (((gmb * 8 + t) * 64) + lane) * 8);
            #pragma unroll
            for (int j = 0; j < 8; j++) {
                short8 b = *(const short8*)(Wp + (((size_t)(8 * ch + j) * 8 + t) * 64 + lane) * 8);
                acc[j] = __builtin_amdgcn_mfma_f32_16x16x32_bf16(a, b, acc[j], 0, 0, 0);
            }
        }
    };
    auto store_lds = [&](bf16* buf, const f32x4* acc, float scale) {
        #pragma unroll
        for (int j = 0; j < 8; j++) {
            int col = 128 * ch + 16 * j + m16;
            #pragma unroll
            for (int r = 0; r < 4; r++)
                buf[(R0 + qq * 4 + r) * PITCH + col] = __float2bfloat16(acc[j][r] * scale);
        }
    };
    auto store_gelu = [&](bf16* buf, const f32x4* acc) {
        #pragma unroll
        for (int j = 0; j < 8; j++) {
            int col = 128 * ch + 16 * j + m16;
            #pragma unroll
            for (int r = 0; r < 4; r++)
                buf[(R0 + qq * 4 + r) * PITCH + col] = __float2bfloat16(gelu_tanh(acc[j][r]));
        }
    };
    auto store_vT = [&](const f32x4* acc) {
        #pragma unroll
        for (int j = 0; j < 8; j++) {
            int col = 128 * ch + 16 * j + m16;
            #pragma unroll
            for (int r = 0; r < 4; r++)
                kbuf[col * VT_PITCH + R0 + qq * 4 + r] = __float2bfloat16(acc[j][r]);
        }
    };

    f32x4 acc[8];
    unsigned pf[4][2];
    const short8 zero8 = {0, 0, 0, 0, 0, 0, 0, 0};
    const f32x4 zero4 = {0.0f, 0.0f, 0.0f, 0.0f};

    for (int l = 0; l < 8; l++) {
        // --- LN1 -> y1 (ybuf) ---
        layernorm_to_ybuf(ln1g + l * 256, ln1b + l * 256);
        // --- q = y1 @ Wq + bq, scaled by 1/sqrt(32), into ybuf (own region) ---
        initb(bqp + l * 256, acc);
        gemm_lds(ybuf, Wqp + (size_t)l * 65536, 8, 8 * ch, 0, acc);
        __syncthreads();   // all y1 reads done before overwrite
        store_lds(ybuf, acc, 0.17677669529663687f);
        // --- k = ctx @ Wk + bk -> kbuf row-major (own region) ---
        initb(bkp + l * 256, acc);
        gemm_ctx(Wkp + (size_t)l * 65536, acc);
        store_lds(kbuf, acc, 1.0f);
        // --- attention S^T = K·Q^T per head (wave-local), softmax -> P frags ---
        #pragma unroll
        for (int hh = 0; hh < 4; hh++) {
            int coff = 128 * ch + hh * 32;
            short8 ak = *(const short8*)(kbuf + (R0 + m16) * PITCH + coff + qq * 8);
            short8 aq = *(const short8*)(ybuf + (R0 + m16) * PITCH + coff + qq * 8);
            f32x4 s = __builtin_amdgcn_mfma_f32_16x16x32_bf16(ak, aq, zero4, 0, 0, 0);
            bool valid = ((qq >> 1) == (m16 >> 3));
            float mx = valid ? fmaxf(fmaxf(s[0], s[1]), fmaxf(s[2], s[3])) : -1e30f;
            mx = fmaxf(mx, __shfl_xor(mx, 16, 64));
            mx = fmaxf(mx, __shfl_xor(mx, 32, 64));
            float p[4];
            #pragma unroll
            for (int r = 0; r < 4; r++) p[r] = valid ? __expf(s[r] - mx) : 0.0f;
            float ds = p[0] + p[1] + p[2] + p[3];
            ds += __shfl_xor(ds, 16, 64);
            ds += __shfl_xor(ds, 32, 64);
            float inv = 1.0f / ds;
            union { bf16 h[2]; unsigned u; } cv;
            cv.h[0] = __float2bfloat16(p[0] * inv); cv.h[1] = __float2bfloat16(p[1] * inv);
            pf[hh][0] = cv.u;
            cv.h[0] = __float2bfloat16(p[2] * inv); cv.h[1] = __float2bfloat16(p[3] * inv);
            pf[hh][1] = cv.u;
        }
        // --- v = ctx @ Wv + bv (global reads only) ---
        initb(bvp + l * 256, acc);
        gemm_ctx(Wvp + (size_t)l * 65536, acc);
        __syncthreads();   // all S reads of kbuf done block-wide
        store_vT(acc);
        // --- O = P·V  (16x16x32, k zero-padded 16->32) -> ybuf (own region) ---
        #pragma unroll
        for (int hh = 0; hh < 4; hh++) {
            #pragma unroll
            for (int hf = 0; hf < 2; hf++) {
                int src0 = ((2 * qq) & 3) * 16 + m16;
                int src1 = ((2 * qq + 1) & 3) * 16 + m16;
                unsigned u0 = (unsigned)__shfl((int)pf[hh][0], src0, 64);
                unsigned u1 = (unsigned)__shfl((int)pf[hh][1], src0, 64);
                unsigned u2 = (unsigned)__shfl((int)pf[hh][0], src1, 64);
                unsigned u3 = (unsigned)__shfl((int)pf[hh][1], src1, 64);
                union { unsigned u[4]; short8 s; } av;
                if (qq >= 2) { av.u[0] = av.u[1] = av.u[2] = av.u[3] = 0; }
                else { av.u[0] = u0; av.u[1] = u1; av.u[2] = u2; av.u[3] = u3; }
                short8 bv8 = zero8;
                if (qq < 2)
                    bv8 = *(const short8*)(kbuf + (128 * ch + hh * 32 + hf * 16 + m16) * VT_PITCH
                                           + R0 + qq * 8);
                acc[hh * 2 + hf] = __builtin_amdgcn_mfma_f32_16x16x32_bf16(av.s, bv8, zero4, 0, 0, 0);
            }
        }
        store_lds(ybuf, acc, 1.0f);
        __syncthreads();   // O visible to both ch halves
        // --- tr += O @ Wo + bo ---
        gemm_lds(ybuf, Wop + (size_t)l * 65536, 8, 8 * ch, 0, tr);
        #pragma unroll
        for (int j = 0; j < 8; j++) {
            float bv2 = bop[l * 256 + 128 * ch + 16 * j + m16];
            #pragma unroll
            for (int r = 0; r < 4; r++) tr[j][r] += bv2;
        }
        __syncthreads();   // o-proj ybuf reads done before y2 overwrite
        // --- LN2 -> y2 (ybuf) ---
        layernorm_to_ybuf(ln2g + l * 256, ln2b + l * 256);
        // --- FFN in 4 chunks of 256 hidden cols; h via kbuf; tr += h @ W2 ---
        for (int nc = 0; nc < 4; nc++) {
            initb(b1p + l * 1024 + nc * 256, acc);
            gemm_lds(ybuf, W1p + (size_t)l * 262144, 8, nc * 16 + 8 * ch, 0, acc);
            __syncthreads();   // previous kbuf readers done
            store_gelu(kbuf, acc);
            __syncthreads();   // h visible
            gemm_lds(kbuf, W2p + (size_t)l * 262144, 32, 8 * ch, nc * 8, tr);
        }
        #pragma unroll
        for (int j = 0; j < 8; j++) {
            float bv2 = b2p[l * 256 + 128 * ch + 16 * j + m16];
            #pragma unroll
            for (int r = 0; r < 4; r++) tr[j][r] += bv2;
        }
    }
    // --- write final tr (bf16) ---
    #pragma unroll
    for (int j = 0; j < 8; j++) {
        int col = 128 * ch + 16 * j + m16;
        #pragma unroll
        for (int r = 0; r < 4; r++)
            trb[((size_t)blockIdx.x * 48 + R0 + qq * 4 + r) * 256 + col] = __float2bfloat16(tr[j][r]);
    }
}

extern "C" void kernel_launch(void* const* d_in, const int* in_sizes, int n_in,
                              void* d_out, int out_size, void* d_ws, size_t ws_size,
                              hipStream_t stream) {
    const float* x     = (const float*)d_in[0];
    const int*   li    = (const int*)d_in[1];
    const float* mlp_w = (const float*)d_in[2];
    const float* mlp_b = (const float*)d_in[3];
    const float* bg    = (const float*)d_in[4];
    const float* ln1_g = (const float*)d_in[5];
    const float* ln1_b = (const float*)d_in[6];
    const float* wq    = (const float*)d_in[7];
    const float* bq    = (const float*)d_in[8];
    const float* wk    = (const float*)d_in[9];
    const float* bk    = (const float*)d_in[10];
    const float* wv    = (const float*)d_in[11];
    const float* bv    = (const float*)d_in[12];
    const float* wo    = (const float*)d_in[13];
    const float* bo    = (const float*)d_in[14];
    const float* ln2_g = (const float*)d_in[15];
    const float* ln2_b = (const float*)d_in[16];
    const float* w1    = (const float*)d_in[17];
    const float* b1    = (const float*)d_in[18];
    const float* w2    = (const float*)d_in[19];
    const float* b2    = (const float*)d_in[20];
    const float* pw    = (const float*)d_in[21];
    const float* pb    = (const float*)d_in[22];

    char* p = (char*)d_ws;
    auto carve = [&](size_t bytes) {
        char* r = p;
        p += (bytes + 255) & ~(size_t)255;
        return r;
    };
    int*  cnt  = (int*)carve(NB * 4);
    int*  dst  = (int*)carve(N_OBS * 4);
    bf16* mlpT = (bf16*)carve((size_t)3 * 65536 * 2);
    bf16* Wqp  = (bf16*)carve((size_t)8 * 65536 * 2);
    bf16* Wkp  = (bf16*)carve((size_t)8 * 65536 * 2);
    bf16* Wvp  = (bf16*)carve((size_t)8 * 65536 * 2);
    bf16* Wop  = (bf16*)carve((size_t)8 * 65536 * 2);
    bf16* W1p  = (bf16*)carve((size_t)8 * 262144 * 2);
    bf16* W2p  = (bf16*)carve((size_t)8 * 262144 * 2);
    bf16* pwT  = (bf16*)carve((size_t)2048 * 512 * 2);
    bf16* tmpA = (bf16*)carve((size_t)MPAD * 256 * 2);
    bf16* tmpB = (bf16*)carve((size_t)MPAD * 256 * 2);
    bf16* ctxp = (bf16*)carve((size_t)N_OBS * 256 * 2);
    bf16* trb  = (bf16*)carve((size_t)18612224 * 2);  // 9088*2048 (proj reads padded rows)

    hipMemsetAsync(cnt, 0, NB * 4, stream);
    slot_kernel<<<(N_OBS + 255) / 256, 256, 0, stream>>>(li, cnt, dst);

    wtrans<<<dim3(256, 3), 256, 0, stream>>>(mlp_w, mlpT, 256, 256);
    pack_b<<<dim3(256, 8), 256, 0, stream>>>(wq, Wqp, 256, 256);
    pack_b<<<dim3(256, 8), 256, 0, stream>>>(wk, Wkp, 256, 256);
    pack_b<<<dim3(256, 8), 256, 0, stream>>>(wv, Wvp, 256, 256);
    pack_b<<<dim3(256, 8), 256, 0, stream>>>(wo, Wop, 256, 256);
    pack_b<<<dim3(1024, 8), 256, 0, stream>>>(w1, W1p, 256, 1024);
    pack_b<<<dim3(1024, 8), 256, 0, stream>>>(w2, W2p, 1024, 256);
    wtrans<<<dim3(4096, 1), 256, 0, stream>>>(pw, pwT, 2048, 512);

    convx<<<18016, 256, 0, stream>>>(x, tmpA);

    dim3 blk(256), g2(MT, 2);
    // MLP: fc1+gelu, fc2+gelu, fc3 -> ctx packed in A-fragment order
    gemm_bt<true, 0><<<g2, blk, 0, stream>>>(tmpA, 256, mlpT, 256, mlp_b,
        tmpB, nullptr, 256, nullptr, 0, 256, 0);
    gemm_bt<true, 0><<<g2, blk, 0, stream>>>(tmpB, 256, mlpT + 65536, 256, mlp_b + 256,
        tmpA, nullptr, 256, nullptr, 0, 256, 0);
    gemm_bt<false, 3><<<g2, blk, 0, stream>>>(tmpA, 256, mlpT + 131072, 256, mlp_b + 512,
        ctxp, nullptr, 256, dst, N_OBS, 256, 0);

    // fused transformer: 1500 blocks x 6 buckets
    fused_tr<<<1500, 384, 0, stream>>>(ctxp, Wqp, Wkp, Wvp, Wop, W1p, W2p,
        bg, ln1_g, ln1_b, bq, bk, bv, bo, ln2_g, ln2_b, b1, b2, trb);

    // final projection: [9000,2048] @ [2048,512] -> d_out (fp32)
    gemm_bt<false, 2><<<dim3(71, 4), blk, 0, stream>>>(trb, 2048, pwT, 2048, pb,
        nullptr, (float*)d_out, 512, nullptr, 0, 2048, NB);
}

// Round 3
// 3327.695 us; speedup vs baseline: 3.4190x; 3.4190x over previous
//
#include <hip/hip_runtime.h>
#include <hip/hip_bf16.h>
#include <cstdint>
#include <cstddef>

typedef __hip_bfloat16 bf16;
typedef __attribute__((ext_vector_type(8))) short short8;
typedef __attribute__((ext_vector_type(4))) float f32x4;

struct __align__(8) bf16x4_s { bf16 x, y, z, w; };

#define N_OBS 72000
#define NB 9000
#define MPAD 72064   /* 563*128 */
#define MT 563
#define PITCH 264    /* bf16 elems; odd multiple of 8 -> bank spread; rows 16B aligned */
#define VT_PITCH 104 /* vT col stride: 96 rows + 8 pad; 208B, 16B aligned */
#define ROWS_PB 96

#define MFMA16 __builtin_amdgcn_mfma_f32_16x16x32_bf16

__device__ __forceinline__ float gelu_tanh(float x) {
    const float c = 0.7978845608028654f;
    float x3 = x * x * x;
    return 0.5f * x * (1.0f + tanhf(c * (x + 0.044715f * x3)));
}

__device__ __forceinline__ void gload16(const bf16* g, bf16* l) {
    __builtin_amdgcn_global_load_lds(
        (const __attribute__((address_space(1))) unsigned int*)g,
        (__attribute__((address_space(3))) unsigned int*)l, 16, 0, 0);
}

// ---------------- slot assignment (permutation-invariant scatter) ----------------
__global__ void slot_kernel(const int* __restrict__ li, int* __restrict__ cnt,
                            int* __restrict__ dst) {
    int i = blockIdx.x * 256 + threadIdx.x;
    if (i >= N_OBS) return;
    int d = li[i * 3], h = li[i * 3 + 1], w = li[i * 3 + 2];
    int flat = d * 1800 + h * 60 + w;
    int slot = atomicAdd(&cnt[flat], 1);
    dst[i] = flat * 8 + slot;
}

// ---------------- weight fp32 [B,K,N] -> bf16 [B,N,K] (row-major Bt) ----------------
__global__ void wtrans(const float* __restrict__ W, bf16* __restrict__ Wt,
                       int K, int N) {
    size_t off = (size_t)blockIdx.y * K * N;
    int idx = blockIdx.x * 256 + threadIdx.x;
    if (idx >= K * N) return;
    int k = idx / N, n = idx % N;
    Wt[off + (size_t)n * K + k] = __float2bfloat16(W[off + idx]);
}

// ---------------- weight fp32 [B,K,N] -> chunked MFMA-B-fragment layout ----------------
// slab s = n>>8 (256-col slabs); within slab: chunk kb = k>>5 (16KB each);
// in-chunk: ((np>>4)*64 + ((k>>3)&3)*16 + (np&15))*8 + (k&7)
__global__ void pack_w(const float* __restrict__ W, bf16* __restrict__ P,
                       int K, int N) {
    size_t off = (size_t)blockIdx.y * K * N;
    int idx = blockIdx.x * 256 + threadIdx.x;
    if (idx >= K * N) return;
    int k = idx / N, n = idx % N;
    int np = n & 255;
    size_t dst = (size_t)(n >> 8) * ((size_t)K * 256)
               + (size_t)(k >> 5) * 8192
               + (size_t)(((np >> 4) * 64) + ((k >> 3) & 3) * 16 + (np & 15)) * 8 + (k & 7);
    P[off + dst] = __float2bfloat16(W[off + idx]);
}

// ---------------- x fp32 -> bf16 padded ----------------
__global__ void convx(const float* __restrict__ X, bf16* __restrict__ Y) {
    size_t base = ((size_t)blockIdx.x * 256 + threadIdx.x) * 4;
    size_t row = base >> 8;
    bf16 z = __float2bfloat16(0.0f);
    bf16x4_s o = {z, z, z, z};
    if (row < N_OBS) {
        float4 v = *(const float4*)(X + base);
        o.x = __float2bfloat16(v.x); o.y = __float2bfloat16(v.y);
        o.z = __float2bfloat16(v.z); o.w = __float2bfloat16(v.w);
    }
    *(bf16x4_s*)(Y + base) = o;
}

// ---------------- MFMA GEMM: C[M,N] = act(A[M,K] @ Bt[N,K]^T + bias) ----------------
// MODE: 0 = bf16 out, 2 = fp32 out rows<Mstore, 3 = bf16 A-frag-packed scatter out
template <bool GELU, int MODE>
__global__ __launch_bounds__(256, 2) void gemm_bt(
    const bf16* __restrict__ A, int lda,
    const bf16* __restrict__ Bt, int ldb,
    const float* __restrict__ bias,
    bf16* __restrict__ Cb, float* __restrict__ Cf, int ldc,
    const int* __restrict__ scatter, int scatterN,
    int K, int Mstore) {
    __shared__ __align__(16) bf16 As[128 * 40];
    __shared__ __align__(16) bf16 Bs[128 * 40];
    const int tid = threadIdx.x;
    const int m0 = blockIdx.x * 128;
    const int n0 = blockIdx.y * 128;
    const int wave = tid >> 6, lane = tid & 63;
    const int wm = (wave & 1) * 64, wn = (wave >> 1) * 64;
    const int m16 = lane & 15, qq = lane >> 4;

    f32x4 acc[4][4];
    #pragma unroll
    for (int i = 0; i < 4; i++)
        #pragma unroll
        for (int j = 0; j < 4; j++)
            acc[i][j] = {0.0f, 0.0f, 0.0f, 0.0f};

    const int lrow = tid >> 2;
    const int lq = (tid & 3) * 8;

    for (int k0 = 0; k0 < K; k0 += 32) {
        const uint4 av0 = *(const uint4*)(A + (size_t)(m0 + lrow) * lda + k0 + lq);
        const uint4 av1 = *(const uint4*)(A + (size_t)(m0 + lrow + 64) * lda + k0 + lq);
        const uint4 bv0 = *(const uint4*)(Bt + (size_t)(n0 + lrow) * ldb + k0 + lq);
        const uint4 bv1 = *(const uint4*)(Bt + (size_t)(n0 + lrow + 64) * ldb + k0 + lq);
        *(uint4*)(As + lrow * 40 + lq) = av0;
        *(uint4*)(As + (lrow + 64) * 40 + lq) = av1;
        *(uint4*)(Bs + lrow * 40 + lq) = bv0;
        *(uint4*)(Bs + (lrow + 64) * 40 + lq) = bv1;
        __syncthreads();
        short8 a[4], b[4];
        #pragma unroll
        for (int i = 0; i < 4; i++)
            a[i] = *(const short8*)(As + (wm + i * 16 + m16) * 40 + qq * 8);
        #pragma unroll
        for (int j = 0; j < 4; j++)
            b[j] = *(const short8*)(Bs + (wn + j * 16 + m16) * 40 + qq * 8);
        #pragma unroll
        for (int i = 0; i < 4; i++)
            #pragma unroll
            for (int j = 0; j < 4; j++)
                acc[i][j] = MFMA16(a[i], b[j], acc[i][j], 0, 0, 0);
        __syncthreads();
    }

    #pragma unroll
    for (int i = 0; i < 4; i++) {
        #pragma unroll
        for (int j = 0; j < 4; j++) {
            const int col = n0 + wn + j * 16 + m16;
            const float bs = bias ? bias[col] : 0.0f;
            #pragma unroll
            for (int r = 0; r < 4; r++) {
                int row = m0 + wm + i * 16 + qq * 4 + r;
                float v = acc[i][j][r] + bs;
                if (GELU) v = gelu_tanh(v);
                if (MODE == 0) {
                    Cb[(size_t)row * ldc + col] = __float2bfloat16(v);
                } else if (MODE == 2) {
                    if (row < Mstore) Cf[(size_t)row * ldc + col] = v;
                } else if (MODE == 3) {
                    if (row < scatterN) {
                        int orow = scatter[row];
                        size_t off = (((size_t)(orow >> 4) * 8 + (col >> 5)) * 64
                                      + ((col >> 3) & 3) * 16 + (orow & 15)) * 8 + (col & 7);
                        Cb[off] = __float2bfloat16(v);
                    }
                }
            }
        }
    }
}

// ================= fused 8-layer transformer, LDS-streamed weights =================
// 384 thr = 6 waves; 96 rows (12 buckets)/block; wave (rb,ch): rows 32rb..+31, cols 128ch..+127
__global__ __launch_bounds__(384, 2) void fused_tr(
    const bf16* __restrict__ ctxp,
    const bf16* __restrict__ Wqp, const bf16* __restrict__ Wkp,
    const bf16* __restrict__ Wvp, const bf16* __restrict__ Wop,
    const bf16* __restrict__ W1p, const bf16* __restrict__ W2p,
    const float* __restrict__ bg,
    const float* __restrict__ ln1g, const float* __restrict__ ln1b,
    const float* __restrict__ bqp, const float* __restrict__ bkp,
    const float* __restrict__ bvp, const float* __restrict__ bop,
    const float* __restrict__ ln2g, const float* __restrict__ ln2b,
    const float* __restrict__ b1p, const float* __restrict__ b2p,
    bf16* __restrict__ trb)
{
    __shared__ __align__(16) bf16 ybuf[ROWS_PB * PITCH];     // 50688 B
    __shared__ __align__(16) bf16 kvbuf[256 * VT_PITCH];     // 53248 B (k / vT / h)
    __shared__ __align__(16) bf16 wstage[2 * 8192];          // 32768 B weight chunks
    __shared__ float2 lnred[2][ROWS_PB];                     // 1536 B

    const int tid = threadIdx.x;
    const int wave = tid >> 6, lane = tid & 63;
    const int m16 = lane & 15, qq = lane >> 4;
    const int ch = (wave >= 3) ? 1 : 0;
    const int rb = wave - 3 * ch;
    const int R0 = rb * 32;
    const int g0 = blockIdx.x * 6 + rb * 2;   // 16-row ctx group for i=0

    const f32x4 zero4 = {0.0f, 0.0f, 0.0f, 0.0f};
    const short8 zero8 = {0, 0, 0, 0, 0, 0, 0, 0};

    // ---- cooperative 16KB chunk stage: 1024 slots of 16B ----
    auto stage = [&](const bf16* src, int sel) {
        bf16* dst = wstage + sel * 8192;
        gload16(src + ((wave * 64 + lane) << 3), dst + ((wave * 64) << 3));
        gload16(src + ((384 + wave * 64 + lane) << 3), dst + ((384 + wave * 64) << 3));
        if (wave < 4)
            gload16(src + ((768 + wave * 64 + lane) << 3), dst + ((768 + wave * 64) << 3));
    };

    auto stream_gemm = [&](auto getA, const bf16* Wb, f32x4 (&acc)[2][8]) {
        stage(Wb, 0);
        __syncthreads();
        #pragma unroll
        for (int t = 0; t < 8; t++) {
            if (t < 7) stage(Wb + (size_t)(t + 1) * 8192, (t + 1) & 1);
            short8 a0 = getA(0, t);
            short8 a1 = getA(1, t);
            const bf16* wb = wstage + (t & 1) * 8192;
            #pragma unroll
            for (int j = 0; j < 8; j++) {
                short8 b = *(const short8*)(wb + (((8 * ch + j) * 64 + lane) << 3));
                acc[0][j] = MFMA16(a0, b, acc[0][j], 0, 0, 0);
                acc[1][j] = MFMA16(a1, b, acc[1][j], 0, 0, 0);
            }
            __syncthreads();
        }
    };

    auto aY = [&](int i, int t) {
        return *(const short8*)(ybuf + (R0 + 16 * i + m16) * PITCH + t * 32 + qq * 8);
    };
    auto aH = [&](int i, int t) {
        return *(const short8*)(kvbuf + (R0 + 16 * i + m16) * PITCH + t * 32 + qq * 8);
    };
    auto aC = [&](int i, int t) {
        return *(const short8*)(ctxp + (((size_t)(g0 + i) * 8 + t) * 64 + lane) * 8);
    };

    f32x4 tr[2][8];
    #pragma unroll
    for (int i = 0; i < 2; i++)
        #pragma unroll
        for (int j = 0; j < 8; j++) {
            int col = 128 * ch + 16 * j + m16;
            #pragma unroll
            for (int r = 0; r < 4; r++)
                tr[i][j][r] = bg[((qq * 4 + r) & 7) * 256 + col];
        }

    auto layernorm_to_ybuf = [&](const float* g, const float* b) {
        float mean[2][4], rstd[2][4];
        #pragma unroll
        for (int i = 0; i < 2; i++) {
            float s[4] = {0, 0, 0, 0}, s2[4] = {0, 0, 0, 0};
            #pragma unroll
            for (int j = 0; j < 8; j++)
                #pragma unroll
                for (int r = 0; r < 4; r++) { float v = tr[i][j][r]; s[r] += v; s2[r] += v * v; }
            #pragma unroll
            for (int m = 1; m < 16; m <<= 1)
                #pragma unroll
                for (int r = 0; r < 4; r++) {
                    s[r] += __shfl_xor(s[r], m, 64);
                    s2[r] += __shfl_xor(s2[r], m, 64);
                }
            if (m16 == 0) {
                #pragma unroll
                for (int r = 0; r < 4; r++)
                    lnred[ch][R0 + 16 * i + qq * 4 + r] = make_float2(s[r], s2[r]);
            }
        }
        __syncthreads();
        #pragma unroll
        for (int i = 0; i < 2; i++)
            #pragma unroll
            for (int r = 0; r < 4; r++) {
                float2 a = lnred[0][R0 + 16 * i + qq * 4 + r];
                float2 bb = lnred[1][R0 + 16 * i + qq * 4 + r];
                float su = a.x + bb.x, sq = a.y + bb.y;
                mean[i][r] = su * (1.0f / 256.0f);
                rstd[i][r] = rsqrtf(sq * (1.0f / 256.0f) - mean[i][r] * mean[i][r] + 1e-5f);
            }
        #pragma unroll
        for (int i = 0; i < 2; i++)
            #pragma unroll
            for (int j = 0; j < 8; j++) {
                int col = 128 * ch + 16 * j + m16;
                float gv = g[col], bv2 = b[col];
                #pragma unroll
                for (int r = 0; r < 4; r++) {
                    float y = (tr[i][j][r] - mean[i][r]) * rstd[i][r] * gv + bv2;
                    ybuf[(R0 + 16 * i + qq * 4 + r) * PITCH + col] = __float2bfloat16(y);
                }
            }
    };

    auto initb = [&](const float* bias, f32x4 (&acc)[2][8]) {
        #pragma unroll
        for (int j = 0; j < 8; j++) {
            float bv2 = bias[128 * ch + 16 * j + m16];
            acc[0][j] = {bv2, bv2, bv2, bv2};
            acc[1][j] = {bv2, bv2, bv2, bv2};
        }
    };
    auto store_buf = [&](bf16* buf, f32x4 (&acc)[2][8], float scale) {
        #pragma unroll
        for (int i = 0; i < 2; i++)
            #pragma unroll
            for (int j = 0; j < 8; j++) {
                int col = 128 * ch + 16 * j + m16;
                #pragma unroll
                for (int r = 0; r < 4; r++)
                    buf[(R0 + 16 * i + qq * 4 + r) * PITCH + col] =
                        __float2bfloat16(acc[i][j][r] * scale);
            }
    };
    auto store_gelu_h = [&](f32x4 (&acc)[2][8]) {
        #pragma unroll
        for (int i = 0; i < 2; i++)
            #pragma unroll
            for (int j = 0; j < 8; j++) {
                int col = 128 * ch + 16 * j + m16;
                #pragma unroll
                for (int r = 0; r < 4; r++)
                    kvbuf[(R0 + 16 * i + qq * 4 + r) * PITCH + col] =
                        __float2bfloat16(gelu_tanh(acc[i][j][r]));
            }
    };
    auto store_vT = [&](f32x4 (&acc)[2][8]) {
        #pragma unroll
        for (int i = 0; i < 2; i++)
            #pragma unroll
            for (int j = 0; j < 8; j++) {
                int col = 128 * ch + 16 * j + m16;
                #pragma unroll
                for (int r = 0; r < 4; r++)
                    kvbuf[col * VT_PITCH + R0 + 16 * i + qq * 4 + r] =
                        __float2bfloat16(acc[i][j][r]);
            }
    };

    f32x4 acc[2][8];
    unsigned pf[2][4][2];

    for (int l = 0; l < 8; l++) {
        // --- LN1 -> y1 ---
        layernorm_to_ybuf(ln1g + l * 256, ln1b + l * 256);
        // --- q = y1 @ Wq + bq (scaled), into ybuf ---
        initb(bqp + l * 256, acc);
        stream_gemm(aY, Wqp + (size_t)l * 65536, acc);
        store_buf(ybuf, acc, 0.17677669529663687f);
        // --- k = ctx @ Wk + bk -> kvbuf row-major ---
        initb(bkp + l * 256, acc);
        stream_gemm(aC, Wkp + (size_t)l * 65536, acc);
        store_buf(kvbuf, acc, 1.0f);
        // --- S^T = K.Q^T per head (wave-local regions), softmax -> P frags ---
        #pragma unroll
        for (int i = 0; i < 2; i++)
            #pragma unroll
            for (int hh = 0; hh < 4; hh++) {
                int coff = 128 * ch + hh * 32;
                short8 ak = *(const short8*)(kvbuf + (R0 + 16 * i + m16) * PITCH + coff + qq * 8);
                short8 aq = *(const short8*)(ybuf + (R0 + 16 * i + m16) * PITCH + coff + qq * 8);
                f32x4 s = MFMA16(ak, aq, zero4, 0, 0, 0);
                bool valid = ((qq >> 1) == (m16 >> 3));
                float mx = valid ? fmaxf(fmaxf(s[0], s[1]), fmaxf(s[2], s[3])) : -1e30f;
                mx = fmaxf(mx, __shfl_xor(mx, 16, 64));
                mx = fmaxf(mx, __shfl_xor(mx, 32, 64));
                float p[4];
                #pragma unroll
                for (int r = 0; r < 4; r++) p[r] = valid ? __expf(s[r] - mx) : 0.0f;
                float ds = p[0] + p[1] + p[2] + p[3];
                ds += __shfl_xor(ds, 16, 64);
                ds += __shfl_xor(ds, 32, 64);
                float inv = 1.0f / ds;
                union { bf16 h[2]; unsigned u; } cv;
                cv.h[0] = __float2bfloat16(p[0] * inv); cv.h[1] = __float2bfloat16(p[1] * inv);
                pf[i][hh][0] = cv.u;
                cv.h[0] = __float2bfloat16(p[2] * inv); cv.h[1] = __float2bfloat16(p[3] * inv);
                pf[i][hh][1] = cv.u;
            }
        // --- v = ctx @ Wv + bv ---
        initb(bvp + l * 256, acc);
        stream_gemm(aC, Wvp + (size_t)l * 65536, acc);
        // trailing barrier of stream_gemm: all S^T k-reads complete block-wide
        store_vT(acc);
        // --- O = P.V (k zero-padded 16->32), reads own vT patch ---
        #pragma unroll
        for (int i = 0; i < 2; i++)
            #pragma unroll
            for (int hh = 0; hh < 4; hh++)
                #pragma unroll
                for (int hf = 0; hf < 2; hf++) {
                    int src0 = ((2 * qq) & 3) * 16 + m16;
                    int src1 = ((2 * qq + 1) & 3) * 16 + m16;
                    unsigned u0 = (unsigned)__shfl((int)pf[i][hh][0], src0, 64);
                    unsigned u1 = (unsigned)__shfl((int)pf[i][hh][1], src0, 64);
                    unsigned u2 = (unsigned)__shfl((int)pf[i][hh][0], src1, 64);
                    unsigned u3 = (unsigned)__shfl((int)pf[i][hh][1], src1, 64);
                    union { unsigned u[4]; short8 s; } av;
                    if (qq >= 2) { av.u[0] = av.u[1] = av.u[2] = av.u[3] = 0; }
                    else { av.u[0] = u0; av.u[1] = u1; av.u[2] = u2; av.u[3] = u3; }
                    short8 bv8 = zero8;
                    if (qq < 2)
                        bv8 = *(const short8*)(kvbuf + (128 * ch + hh * 32 + hf * 16 + m16) * VT_PITCH
                                               + R0 + 16 * i + qq * 8);
                    acc[i][hh * 2 + hf] = MFMA16(av.s, bv8, zero4, 0, 0, 0);
                }
        store_buf(ybuf, acc, 1.0f);   // O overwrites q (q only read by own wave)
        // --- tr += O @ Wo + bo (initial barrier makes O visible across ch) ---
        stream_gemm(aY, Wop + (size_t)l * 65536, tr);
        #pragma unroll
        for (int j = 0; j < 8; j++) {
            float bv2 = bop[l * 256 + 128 * ch + 16 * j + m16];
            #pragma unroll
            for (int r = 0; r < 4; r++) { tr[0][j][r] += bv2; tr[1][j][r] += bv2; }
        }
        // --- LN2 -> y2 ---
        layernorm_to_ybuf(ln2g + l * 256, ln2b + l * 256);
        // --- FFN: 4 chunks of 256 hidden cols ---
        for (int nc = 0; nc < 4; nc++) {
            initb(b1p + l * 1024 + nc * 256, acc);
            stream_gemm(aY, W1p + (size_t)l * 262144 + (size_t)nc * 65536, acc);
            store_gelu_h(acc);
            stream_gemm(aH, W2p + (size_t)l * 262144 + (size_t)nc * 65536, tr);
        }
        #pragma unroll
        for (int j = 0; j < 8; j++) {
            float bv2 = b2p[l * 256 + 128 * ch + 16 * j + m16];
            #pragma unroll
            for (int r = 0; r < 4; r++) { tr[0][j][r] += bv2; tr[1][j][r] += bv2; }
        }
    }
    // --- final write ---
    #pragma unroll
    for (int i = 0; i < 2; i++)
        #pragma unroll
        for (int j = 0; j < 8; j++) {
            int col = 128 * ch + 16 * j + m16;
            #pragma unroll
            for (int r = 0; r < 4; r++)
                trb[((size_t)blockIdx.x * ROWS_PB + R0 + 16 * i + qq * 4 + r) * 256 + col] =
                    __float2bfloat16(tr[i][j][r]);
        }
}

extern "C" void kernel_launch(void* const* d_in, const int* in_sizes, int n_in,
                              void* d_out, int out_size, void* d_ws, size_t ws_size,
                              hipStream_t stream) {
    const float* x     = (const float*)d_in[0];
    const int*   li    = (const int*)d_in[1];
    const float* mlp_w = (const float*)d_in[2];
    const float* mlp_b = (const float*)d_in[3];
    const float* bg    = (const float*)d_in[4];
    const float* ln1_g = (const float*)d_in[5];
    const float* ln1_b = (const float*)d_in[6];
    const float* wq    = (const float*)d_in[7];
    const float* bq    = (const float*)d_in[8];
    const float* wk    = (const float*)d_in[9];
    const float* bk    = (const float*)d_in[10];
    const float* wv    = (const float*)d_in[11];
    const float* bv    = (const float*)d_in[12];
    const float* wo    = (const float*)d_in[13];
    const float* bo    = (const float*)d_in[14];
    const float* ln2_g = (const float*)d_in[15];
    const float* ln2_b = (const float*)d_in[16];
    const float* w1    = (const float*)d_in[17];
    const float* b1    = (const float*)d_in[18];
    const float* w2    = (const float*)d_in[19];
    const float* b2    = (const float*)d_in[20];
    const float* pw    = (const float*)d_in[21];
    const float* pb    = (const float*)d_in[22];

    char* p = (char*)d_ws;
    auto carve = [&](size_t bytes) {
        char* r = p;
        p += (bytes + 255) & ~(size_t)255;
        return r;
    };
    int*  cnt  = (int*)carve(NB * 4);
    int*  dst  = (int*)carve(N_OBS * 4);
    bf16* mlpT = (bf16*)carve((size_t)3 * 65536 * 2);
    bf16* Wqp  = (bf16*)carve((size_t)8 * 65536 * 2);
    bf16* Wkp  = (bf16*)carve((size_t)8 * 65536 * 2);
    bf16* Wvp  = (bf16*)carve((size_t)8 * 65536 * 2);
    bf16* Wop  = (bf16*)carve((size_t)8 * 65536 * 2);
    bf16* W1p  = (bf16*)carve((size_t)8 * 262144 * 2);
    bf16* W2p  = (bf16*)carve((size_t)8 * 262144 * 2);
    bf16* pwT  = (bf16*)carve((size_t)2048 * 512 * 2);
    bf16* tmpA = (bf16*)carve((size_t)MPAD * 256 * 2);
    bf16* tmpB = (bf16*)carve((size_t)MPAD * 256 * 2);
    bf16* ctxp = (bf16*)carve((size_t)N_OBS * 256 * 2);
    bf16* trb  = (bf16*)carve((size_t)18612224 * 2);  // 9088*2048

    hipMemsetAsync(cnt, 0, NB * 4, stream);
    slot_kernel<<<(N_OBS + 255) / 256, 256, 0, stream>>>(li, cnt, dst);

    wtrans<<<dim3(256, 3), 256, 0, stream>>>(mlp_w, mlpT, 256, 256);
    pack_w<<<dim3(256, 8), 256, 0, stream>>>(wq, Wqp, 256, 256);
    pack_w<<<dim3(256, 8), 256, 0, stream>>>(wk, Wkp, 256, 256);
    pack_w<<<dim3(256, 8), 256, 0, stream>>>(wv, Wvp, 256, 256);
    pack_w<<<dim3(256, 8), 256, 0, stream>>>(wo, Wop, 256, 256);
    pack_w<<<dim3(1024, 8), 256, 0, stream>>>(w1, W1p, 256, 1024);
    pack_w<<<dim3(1024, 8), 256, 0, stream>>>(w2, W2p, 1024, 256);
    wtrans<<<dim3(4096, 1), 256, 0, stream>>>(pw, pwT, 2048, 512);

    convx<<<18016, 256, 0, stream>>>(x, tmpA);

    dim3 blk(256), g2(MT, 2);
    // MLP: fc1+gelu, fc2+gelu, fc3 -> ctx packed in A-fragment order
    gemm_bt<true, 0><<<g2, blk, 0, stream>>>(tmpA, 256, mlpT, 256, mlp_b,
        tmpB, nullptr, 256, nullptr, 0, 256, 0);
    gemm_bt<true, 0><<<g2, blk, 0, stream>>>(tmpB, 256, mlpT + 65536, 256, mlp_b + 256,
        tmpA, nullptr, 256, nullptr, 0, 256, 0);
    gemm_bt<false, 3><<<g2, blk, 0, stream>>>(tmpA, 256, mlpT + 131072, 256, mlp_b + 512,
        ctxp, nullptr, 256, dst, N_OBS, 256, 0);

    // fused transformer: 750 blocks x 96 rows (exactly 72000 rows)
    fused_tr<<<750, 384, 0, stream>>>(ctxp, Wqp, Wkp, Wvp, Wop, W1p, W2p,
        bg, ln1_g, ln1_b, bq, bk, bv, bo, ln2_g, ln2_b, b1, b2, trb);

    // final projection: [9000,2048] @ [2048,512] -> d_out (fp32)
    gemm_bt<false, 2><<<dim3(71, 4), blk, 0, stream>>>(trb, 2048, pwT, 2048, pb,
        nullptr, (float*)d_out, 512, nullptr, 0, 2048, NB);
}

// Round 4
// 2447.492 us; speedup vs baseline: 4.6486x; 1.3596x over previous
//
#include <hip/hip_runtime.h>
#include <hip/hip_bf16.h>
#include <cstdint>
#include <cstddef>

typedef __hip_bfloat16 bf16;
typedef __attribute__((ext_vector_type(8))) short short8;
typedef __attribute__((ext_vector_type(4))) float f32x4;

struct __align__(8) bf16x4_s { bf16 x, y, z, w; };

#define N_OBS 72000
#define NB 9000
#define MPAD 72064   /* 563*128 */
#define MT 563
#define VT_PITCH 104 /* vT col stride: 96 rows + 8 pad */

#define MFMA16 __builtin_amdgcn_mfma_f32_16x16x32_bf16

// gelu(x) = 0.5x(1+tanh(c(x+0.044715x^3))) = x * sigmoid(2c(x+0.044715x^3))
__device__ __forceinline__ float gelu_fast(float x) {
    float t = -1.5957691216057308f * x * (1.0f + 0.044715f * x * x);
    return x * __builtin_amdgcn_rcpf(1.0f + __expf(t));
}

__device__ __forceinline__ void gload16(const bf16* g, bf16* l) {
    __builtin_amdgcn_global_load_lds(
        (const __attribute__((address_space(1))) unsigned int*)g,
        (__attribute__((address_space(3))) unsigned int*)l, 16, 0, 0);
}

// ---------------- slot assignment (permutation-invariant scatter) ----------------
__global__ void slot_kernel(const int* __restrict__ li, int* __restrict__ cnt,
                            int* __restrict__ dst) {
    int i = blockIdx.x * 256 + threadIdx.x;
    if (i >= N_OBS) return;
    int d = li[i * 3], h = li[i * 3 + 1], w = li[i * 3 + 2];
    int flat = d * 1800 + h * 60 + w;
    int slot = atomicAdd(&cnt[flat], 1);
    dst[i] = flat * 8 + slot;
}

// ---------------- weight fp32 [B,K,N] -> bf16 [B,N,K] (row-major Bt) ----------------
__global__ void wtrans(const float* __restrict__ W, bf16* __restrict__ Wt,
                       int K, int N) {
    size_t off = (size_t)blockIdx.y * K * N;
    int idx = blockIdx.x * 256 + threadIdx.x;
    if (idx >= K * N) return;
    int k = idx / N, n = idx % N;
    Wt[off + (size_t)n * K + k] = __float2bfloat16(W[off + idx]);
}

// ------- weight fp32 [B,K,N] -> 256-col slabs of 16KB k-chunks in B-frag order -------
__global__ void pack_w(const float* __restrict__ W, bf16* __restrict__ P,
                       int K, int N) {
    size_t off = (size_t)blockIdx.y * K * N;
    int idx = blockIdx.x * 256 + threadIdx.x;
    if (idx >= K * N) return;
    int k = idx / N, n = idx % N;
    int np = n & 255;
    size_t dst = (size_t)(n >> 8) * ((size_t)K * 256)
               + (size_t)(k >> 5) * 8192
               + (size_t)(((np >> 4) * 64) + ((k >> 3) & 3) * 16 + (np & 15)) * 8 + (k & 7);
    P[off + dst] = __float2bfloat16(W[off + idx]);
}

// ---------------- x fp32 -> bf16 padded ----------------
__global__ void convx(const float* __restrict__ X, bf16* __restrict__ Y) {
    size_t base = ((size_t)blockIdx.x * 256 + threadIdx.x) * 4;
    size_t row = base >> 8;
    bf16 z = __float2bfloat16(0.0f);
    bf16x4_s o = {z, z, z, z};
    if (row < N_OBS) {
        float4 v = *(const float4*)(X + base);
        o.x = __float2bfloat16(v.x); o.y = __float2bfloat16(v.y);
        o.z = __float2bfloat16(v.z); o.w = __float2bfloat16(v.w);
    }
    *(bf16x4_s*)(Y + base) = o;
}

// ---------------- MFMA GEMM: C[M,N] = act(A[M,K] @ Bt[N,K]^T + bias) ----------------
// MODE: 0 = bf16 out, 2 = fp32 out rows<Mstore, 3 = bf16 A-frag-packed scatter out
template <bool GELU, int MODE>
__global__ __launch_bounds__(256, 2) void gemm_bt(
    const bf16* __restrict__ A, int lda,
    const bf16* __restrict__ Bt, int ldb,
    const float* __restrict__ bias,
    bf16* __restrict__ Cb, float* __restrict__ Cf, int ldc,
    const int* __restrict__ scatter, int scatterN,
    int K, int Mstore) {
    __shared__ __align__(16) bf16 As[128 * 40];
    __shared__ __align__(16) bf16 Bs[128 * 40];
    const int tid = threadIdx.x;
    const int m0 = blockIdx.x * 128;
    const int n0 = blockIdx.y * 128;
    const int wave = tid >> 6, lane = tid & 63;
    const int wm = (wave & 1) * 64, wn = (wave >> 1) * 64;
    const int m16 = lane & 15, qq = lane >> 4;

    f32x4 acc[4][4];
    #pragma unroll
    for (int i = 0; i < 4; i++)
        #pragma unroll
        for (int j = 0; j < 4; j++)
            acc[i][j] = {0.0f, 0.0f, 0.0f, 0.0f};

    const int lrow = tid >> 2;
    const int lq = (tid & 3) * 8;

    uint4 av0, av1, bv0, bv1;
    auto gload = [&](int k0) {
        av0 = *(const uint4*)(A + (size_t)(m0 + lrow) * lda + k0 + lq);
        av1 = *(const uint4*)(A + (size_t)(m0 + lrow + 64) * lda + k0 + lq);
        bv0 = *(const uint4*)(Bt + (size_t)(n0 + lrow) * ldb + k0 + lq);
        bv1 = *(const uint4*)(Bt + (size_t)(n0 + lrow + 64) * ldb + k0 + lq);
    };
    gload(0);
    for (int k0 = 0; k0 < K; k0 += 32) {
        *(uint4*)(As + lrow * 40 + lq) = av0;
        *(uint4*)(As + (lrow + 64) * 40 + lq) = av1;
        *(uint4*)(Bs + lrow * 40 + lq) = bv0;
        *(uint4*)(Bs + (lrow + 64) * 40 + lq) = bv1;
        __syncthreads();
        if (k0 + 32 < K) gload(k0 + 32);   // prefetch next tile during MFMA
        short8 a[4], b[4];
        #pragma unroll
        for (int i = 0; i < 4; i++)
            a[i] = *(const short8*)(As + (wm + i * 16 + m16) * 40 + qq * 8);
        #pragma unroll
        for (int j = 0; j < 4; j++)
            b[j] = *(const short8*)(Bs + (wn + j * 16 + m16) * 40 + qq * 8);
        #pragma unroll
        for (int i = 0; i < 4; i++)
            #pragma unroll
            for (int j = 0; j < 4; j++)
                acc[i][j] = MFMA16(a[i], b[j], acc[i][j], 0, 0, 0);
        __syncthreads();
    }

    #pragma unroll
    for (int i = 0; i < 4; i++) {
        #pragma unroll
        for (int j = 0; j < 4; j++) {
            const int col = n0 + wn + j * 16 + m16;
            const float bs = bias ? bias[col] : 0.0f;
            #pragma unroll
            for (int r = 0; r < 4; r++) {
                int row = m0 + wm + i * 16 + qq * 4 + r;
                float v = acc[i][j][r] + bs;
                if (GELU) v = gelu_fast(v);
                if (MODE == 0) {
                    Cb[(size_t)row * ldc + col] = __float2bfloat16(v);
                } else if (MODE == 2) {
                    if (row < Mstore) Cf[(size_t)row * ldc + col] = v;
                } else if (MODE == 3) {
                    if (row < scatterN) {
                        int orow = scatter[row];
                        size_t off = (((size_t)(orow >> 4) * 8 + (col >> 5)) * 64
                                      + ((col >> 3) & 3) * 16 + (orow & 15)) * 8 + (col & 7);
                        Cb[off] = __float2bfloat16(v);
                    }
                }
            }
        }
    }
}

// ====== fused 8-layer transformer: producer wave stages weights, 6 consumer waves ======
// 448 thr = 7 waves; 96 rows (12 buckets)/block; consumer wave (rb,ch): rows 32rb..+31,
// cols 128ch..+127. Wave 6 = producer (global_load_lds only -> consumer barriers don't
// drain vmcnt; producer's drain hides under consumer compute).
__global__ __launch_bounds__(448, 1) void fused_tr(
    const bf16* __restrict__ ctxp,
    const bf16* __restrict__ Wqp, const bf16* __restrict__ Wkp,
    const bf16* __restrict__ Wvp, const bf16* __restrict__ Wop,
    const bf16* __restrict__ W1p, const bf16* __restrict__ W2p,
    const float* __restrict__ bg,
    const float* __restrict__ ln1g, const float* __restrict__ ln1b,
    const float* __restrict__ bqp, const float* __restrict__ bkp,
    const float* __restrict__ bvp, const float* __restrict__ bop,
    const float* __restrict__ ln2g, const float* __restrict__ ln2b,
    const float* __restrict__ b1p, const float* __restrict__ b2p,
    bf16* __restrict__ trb)
{
    __shared__ __align__(16) bf16 ybuf[96 * 256];    // 49152 B, A-frag packed
    __shared__ __align__(16) bf16 kvh[26624];        // 53248 B: k-packed / vT / h-packed
    __shared__ __align__(16) bf16 wstage[2 * 8192];  // 32768 B weight chunks
    __shared__ float2 lnred[2][96];                  // 1536 B

    const int tid = threadIdx.x;
    const int wave = tid >> 6, lane = tid & 63;
    const int m16 = lane & 15, qq = lane >> 4;
    const bool prod = (wave == 6);
    const int ch = (wave >= 3) ? 1 : 0;          // consumer col half
    const int rb = prod ? 0 : (wave - 3 * ch);   // consumer row block
    const int R0 = rb * 32;
    const int rg0 = rb * 2;                      // 16-row group base
    const size_t gmb = (size_t)blockIdx.x * 6 + rg0;

    const f32x4 zero4 = {0.0f, 0.0f, 0.0f, 0.0f};
    const short8 zero8 = {0, 0, 0, 0, 0, 0, 0, 0};

    // ---- producer: stage one 16KB chunk (1024 x 16B) ----
    auto stage = [&](const bf16* src, int sel) {
        bf16* dst = wstage + (sel << 13);
        #pragma unroll
        for (int s = 0; s < 16; s++)
            gload16(src + ((s * 64 + lane) << 3), dst + ((s * 64) << 3));
    };

    // ---- streamed GEMM, A from packed LDS ----
    auto stream_gemm = [&](const bf16* Abase, const bf16* Wb, f32x4 (&acc)[2][8]) {
        if (prod) stage(Wb, 0);
        __syncthreads();
        #pragma unroll
        for (int t = 0; t < 8; t++) {
            if (prod) {
                if (t < 7) stage(Wb + (size_t)(t + 1) * 8192, (t + 1) & 1);
            } else {
                short8 a0 = *(const short8*)(Abase + ((((rg0) * 8 + t) * 64 + lane) << 3));
                short8 a1 = *(const short8*)(Abase + ((((rg0 + 1) * 8 + t) * 64 + lane) << 3));
                const bf16* wb = wstage + ((t & 1) << 13);
                #pragma unroll
                for (int j = 0; j < 8; j++) {
                    short8 b = *(const short8*)(wb + (((8 * ch + j) * 64 + lane) << 3));
                    acc[0][j] = MFMA16(a0, b, acc[0][j], 0, 0, 0);
                    acc[1][j] = MFMA16(a1, b, acc[1][j], 0, 0, 0);
                }
            }
            __syncthreads();
        }
    };

    // ---- streamed GEMM, A = ctx frags from global (register prefetch) ----
    auto stream_gemm_ctx = [&](const bf16* Wb, f32x4 (&acc)[2][8]) {
        short8 a0n, a1n;
        if (prod) {
            stage(Wb, 0);
        } else {
            a0n = *(const short8*)(ctxp + ((gmb * 8 + 0) * 64 + lane) * 8);
            a1n = *(const short8*)(ctxp + (((gmb + 1) * 8 + 0) * 64 + lane) * 8);
        }
        __syncthreads();
        #pragma unroll
        for (int t = 0; t < 8; t++) {
            if (prod) {
                if (t < 7) stage(Wb + (size_t)(t + 1) * 8192, (t + 1) & 1);
            } else {
                short8 a0 = a0n, a1 = a1n;
                if (t < 7) {
                    a0n = *(const short8*)(ctxp + ((gmb * 8 + t + 1) * 64 + lane) * 8);
                    a1n = *(const short8*)(ctxp + (((gmb + 1) * 8 + t + 1) * 64 + lane) * 8);
                }
                const bf16* wb = wstage + ((t & 1) << 13);
                #pragma unroll
                for (int j = 0; j < 8; j++) {
                    short8 b = *(const short8*)(wb + (((8 * ch + j) * 64 + lane) << 3));
                    acc[0][j] = MFMA16(a0, b, acc[0][j], 0, 0, 0);
                    acc[1][j] = MFMA16(a1, b, acc[1][j], 0, 0, 0);
                }
            }
            __syncthreads();
        }
    };

    f32x4 tr[2][8];
    if (!prod) {
        #pragma unroll
        for (int i = 0; i < 2; i++)
            #pragma unroll
            for (int j = 0; j < 8; j++) {
                int col = 128 * ch + 16 * j + m16;
                #pragma unroll
                for (int r = 0; r < 4; r++)
                    tr[i][j][r] = bg[((qq * 4 + r) & 7) * 256 + col];
            }
    }

    // C-frag (i,j,r) -> packed A-layout offset in a 96x256 buffer
    auto pk = [&](int i, int j) {
        int kb = 4 * ch + (j >> 1);
        int w16 = (2 * j + (m16 >> 3)) & 3;
        return ((((rg0 + i) * 8 + kb) * 64 + w16 * 16 + qq * 4) << 3) + (m16 & 7);
    };

    auto layernorm_to_ybuf = [&](const float* g, const float* b) {
        float mean[2][4], rstd[2][4];
        if (!prod) {
            #pragma unroll
            for (int i = 0; i < 2; i++) {
                float s[4] = {0, 0, 0, 0}, s2[4] = {0, 0, 0, 0};
                #pragma unroll
                for (int j = 0; j < 8; j++)
                    #pragma unroll
                    for (int r = 0; r < 4; r++) { float v = tr[i][j][r]; s[r] += v; s2[r] += v * v; }
                #pragma unroll
                for (int m = 1; m < 16; m <<= 1)
                    #pragma unroll
                    for (int r = 0; r < 4; r++) {
                        s[r] += __shfl_xor(s[r], m, 64);
                        s2[r] += __shfl_xor(s2[r], m, 64);
                    }
                if (m16 == 0) {
                    #pragma unroll
                    for (int r = 0; r < 4; r++)
                        lnred[ch][R0 + 16 * i + qq * 4 + r] = make_float2(s[r], s2[r]);
                }
            }
        }
        __syncthreads();
        if (!prod) {
            #pragma unroll
            for (int i = 0; i < 2; i++)
                #pragma unroll
                for (int r = 0; r < 4; r++) {
                    float2 a = lnred[0][R0 + 16 * i + qq * 4 + r];
                    float2 bb = lnred[1][R0 + 16 * i + qq * 4 + r];
                    float su = a.x + bb.x, sq = a.y + bb.y;
                    mean[i][r] = su * (1.0f / 256.0f);
                    rstd[i][r] = rsqrtf(sq * (1.0f / 256.0f) - mean[i][r] * mean[i][r] + 1e-5f);
                }
            #pragma unroll
            for (int i = 0; i < 2; i++)
                #pragma unroll
                for (int j = 0; j < 8; j++) {
                    int col = 128 * ch + 16 * j + m16;
                    float gv = g[col], bv2 = b[col];
                    int base = pk(i, j);
                    #pragma unroll
                    for (int r = 0; r < 4; r++) {
                        float y = (tr[i][j][r] - mean[i][r]) * rstd[i][r] * gv + bv2;
                        ybuf[base + r * 8] = __float2bfloat16(y);
                    }
                }
        }
        // cross-ch visibility of y provided by next stream_gemm's initial barrier
    };

    auto initb = [&](const float* bias, f32x4 (&acc)[2][8]) {
        if (prod) return;
        #pragma unroll
        for (int j = 0; j < 8; j++) {
            float bv2 = bias[128 * ch + 16 * j + m16];
            acc[0][j] = {bv2, bv2, bv2, bv2};
            acc[1][j] = {bv2, bv2, bv2, bv2};
        }
    };
    auto store_packed = [&](bf16* buf, f32x4 (&acc)[2][8], float scale) {
        if (prod) return;
        #pragma unroll
        for (int i = 0; i < 2; i++)
            #pragma unroll
            for (int j = 0; j < 8; j++) {
                int base = pk(i, j);
                #pragma unroll
                for (int r = 0; r < 4; r++)
                    buf[base + r * 8] = __float2bfloat16(acc[i][j][r] * scale);
            }
    };
    auto store_gelu_packed = [&](f32x4 (&acc)[2][8]) {
        if (prod) return;
        #pragma unroll
        for (int i = 0; i < 2; i++)
            #pragma unroll
            for (int j = 0; j < 8; j++) {
                int base = pk(i, j);
                #pragma unroll
                for (int r = 0; r < 4; r++)
                    kvh[base + r * 8] = __float2bfloat16(gelu_fast(acc[i][j][r]));
            }
    };
    auto store_vT = [&](f32x4 (&acc)[2][8]) {
        if (prod) return;
        #pragma unroll
        for (int i = 0; i < 2; i++)
            #pragma unroll
            for (int j = 0; j < 8; j++) {
                int col = 128 * ch + 16 * j + m16;
                #pragma unroll
                for (int r = 0; r < 4; r++)
                    kvh[col * VT_PITCH + R0 + 16 * i + qq * 4 + r] =
                        __float2bfloat16(acc[i][j][r]);
            }
    };

    f32x4 acc[2][8];
    unsigned pf[2][4][2];

    for (int l = 0; l < 8; l++) {
        // --- LN1 -> y1 (packed ybuf) ---
        layernorm_to_ybuf(ln1g + l * 256, ln1b + l * 256);
        // --- q = y1 @ Wq + bq (scaled), back into ybuf ---
        initb(bqp + l * 256, acc);
        stream_gemm(ybuf, Wqp + (size_t)l * 65536, acc);
        store_packed(ybuf, acc, 0.17677669529663687f);
        // --- k = ctx @ Wk + bk -> kvh packed ---
        initb(bkp + l * 256, acc);
        stream_gemm_ctx(Wkp + (size_t)l * 65536, acc);
        store_packed(kvh, acc, 1.0f);
        // --- S^T = K.Q^T per head (wave-local), softmax -> P frags ---
        if (!prod) {
            #pragma unroll
            for (int i = 0; i < 2; i++)
                #pragma unroll
                for (int hh = 0; hh < 4; hh++) {
                    int kb = 4 * ch + hh;
                    int fo = (((rg0 + i) * 8 + kb) * 64 + lane) << 3;
                    short8 ak = *(const short8*)(kvh + fo);
                    short8 aq = *(const short8*)(ybuf + fo);
                    f32x4 s = MFMA16(ak, aq, zero4, 0, 0, 0);
                    bool valid = ((qq >> 1) == (m16 >> 3));
                    float mx = valid ? fmaxf(fmaxf(s[0], s[1]), fmaxf(s[2], s[3])) : -1e30f;
                    mx = fmaxf(mx, __shfl_xor(mx, 16, 64));
                    mx = fmaxf(mx, __shfl_xor(mx, 32, 64));
                    float p[4];
                    #pragma unroll
                    for (int r = 0; r < 4; r++) p[r] = valid ? __expf(s[r] - mx) : 0.0f;
                    float ds = p[0] + p[1] + p[2] + p[3];
                    ds += __shfl_xor(ds, 16, 64);
                    ds += __shfl_xor(ds, 32, 64);
                    float inv = __builtin_amdgcn_rcpf(ds);
                    union { bf16 h[2]; unsigned u; } cv;
                    cv.h[0] = __float2bfloat16(p[0] * inv); cv.h[1] = __float2bfloat16(p[1] * inv);
                    pf[i][hh][0] = cv.u;
                    cv.h[0] = __float2bfloat16(p[2] * inv); cv.h[1] = __float2bfloat16(p[3] * inv);
                    pf[i][hh][1] = cv.u;
                }
        }
        // --- v = ctx @ Wv + bv ---
        initb(bvp + l * 256, acc);
        stream_gemm_ctx(Wvp + (size_t)l * 65536, acc);
        // final barrier of stream_gemm: all S^T k-reads done block-wide -> safe to overwrite
        store_vT(acc);
        // --- O = P.V (k zero-padded 16->32), wave-local vT patch ---
        if (!prod) {
            #pragma unroll
            for (int i = 0; i < 2; i++)
                #pragma unroll
                for (int hh = 0; hh < 4; hh++)
                    #pragma unroll
                    for (int hf = 0; hf < 2; hf++) {
                        int src0 = ((2 * qq) & 3) * 16 + m16;
                        int src1 = ((2 * qq + 1) & 3) * 16 + m16;
                        unsigned u0 = (unsigned)__shfl((int)pf[i][hh][0], src0, 64);
                        unsigned u1 = (unsigned)__shfl((int)pf[i][hh][1], src0, 64);
                        unsigned u2 = (unsigned)__shfl((int)pf[i][hh][0], src1, 64);
                        unsigned u3 = (unsigned)__shfl((int)pf[i][hh][1], src1, 64);
                        union { unsigned u[4]; short8 s; } av;
                        if (qq >= 2) { av.u[0] = av.u[1] = av.u[2] = av.u[3] = 0; }
                        else { av.u[0] = u0; av.u[1] = u1; av.u[2] = u2; av.u[3] = u3; }
                        short8 bv8 = zero8;
                        if (qq < 2)
                            bv8 = *(const short8*)(kvh + (128 * ch + hh * 32 + hf * 16 + m16) * VT_PITCH
                                                   + R0 + 16 * i + qq * 8);
                        acc[i][hh * 2 + hf] = MFMA16(av.s, bv8, zero4, 0, 0, 0);
                    }
        }
        store_packed(ybuf, acc, 1.0f);   // O overwrites q (wave-local patches)
        // --- tr += O @ Wo + bo (initial barrier gives cross-ch O visibility) ---
        stream_gemm(ybuf, Wop + (size_t)l * 65536, tr);
        if (!prod) {
            #pragma unroll
            for (int j = 0; j < 8; j++) {
                float bv2 = bop[l * 256 + 128 * ch + 16 * j + m16];
                #pragma unroll
                for (int r = 0; r < 4; r++) { tr[0][j][r] += bv2; tr[1][j][r] += bv2; }
            }
        }
        // --- LN2 -> y2 ---
        layernorm_to_ybuf(ln2g + l * 256, ln2b + l * 256);
        // --- FFN: 4 chunks of 256 hidden cols; h via kvh ---
        for (int nc = 0; nc < 4; nc++) {
            initb(b1p + l * 1024 + nc * 256, acc);
            stream_gemm(ybuf, W1p + (size_t)l * 262144 + (size_t)nc * 65536, acc);
            store_gelu_packed(acc);
            stream_gemm(kvh, W2p + (size_t)l * 262144 + (size_t)nc * 65536, tr);
        }
        if (!prod) {
            #pragma unroll
            for (int j = 0; j < 8; j++) {
                float bv2 = b2p[l * 256 + 128 * ch + 16 * j + m16];
                #pragma unroll
                for (int r = 0; r < 4; r++) { tr[0][j][r] += bv2; tr[1][j][r] += bv2; }
            }
        }
    }
    // --- final write ---
    if (!prod) {
        #pragma unroll
        for (int i = 0; i < 2; i++)
            #pragma unroll
            for (int j = 0; j < 8; j++) {
                int col = 128 * ch + 16 * j + m16;
                #pragma unroll
                for (int r = 0; r < 4; r++)
                    trb[((size_t)blockIdx.x * 96 + R0 + 16 * i + qq * 4 + r) * 256 + col] =
                        __float2bfloat16(tr[i][j][r]);
            }
    }
}

extern "C" void kernel_launch(void* const* d_in, const int* in_sizes, int n_in,
                              void* d_out, int out_size, void* d_ws, size_t ws_size,
                              hipStream_t stream) {
    const float* x     = (const float*)d_in[0];
    const int*   li    = (const int*)d_in[1];
    const float* mlp_w = (const float*)d_in[2];
    const float* mlp_b = (const float*)d_in[3];
    const float* bg    = (const float*)d_in[4];
    const float* ln1_g = (const float*)d_in[5];
    const float* ln1_b = (const float*)d_in[6];
    const float* wq    = (const float*)d_in[7];
    const float* bq    = (const float*)d_in[8];
    const float* wk    = (const float*)d_in[9];
    const float* bk    = (const float*)d_in[10];
    const float* wv    = (const float*)d_in[11];
    const float* bv    = (const float*)d_in[12];
    const float* wo    = (const float*)d_in[13];
    const float* bo    = (const float*)d_in[14];
    const float* ln2_g = (const float*)d_in[15];
    const float* ln2_b = (const float*)d_in[16];
    const float* w1    = (const float*)d_in[17];
    const float* b1    = (const float*)d_in[18];
    const float* w2    = (const float*)d_in[19];
    const float* b2    = (const float*)d_in[20];
    const float* pw    = (const float*)d_in[21];
    const float* pb    = (const float*)d_in[22];

    char* p = (char*)d_ws;
    auto carve = [&](size_t bytes) {
        char* r = p;
        p += (bytes + 255) & ~(size_t)255;
        return r;
    };
    int*  cnt  = (int*)carve(NB * 4);
    int*  dst  = (int*)carve(N_OBS * 4);
    bf16* mlpT = (bf16*)carve((size_t)3 * 65536 * 2);
    bf16* Wqp  = (bf16*)carve((size_t)8 * 65536 * 2);
    bf16* Wkp  = (bf16*)carve((size_t)8 * 65536 * 2);
    bf16* Wvp  = (bf16*)carve((size_t)8 * 65536 * 2);
    bf16* Wop  = (bf16*)carve((size_t)8 * 65536 * 2);
    bf16* W1p  = (bf16*)carve((size_t)8 * 262144 * 2);
    bf16* W2p  = (bf16*)carve((size_t)8 * 262144 * 2);
    bf16* pwT  = (bf16*)carve((size_t)2048 * 512 * 2);
    bf16* tmpA = (bf16*)carve((size_t)MPAD * 256 * 2);
    bf16* tmpB = (bf16*)carve((size_t)MPAD * 256 * 2);
    bf16* ctxp = (bf16*)carve((size_t)N_OBS * 256 * 2);
    bf16* trb  = (bf16*)carve((size_t)18612224 * 2);  // 9088*2048

    hipMemsetAsync(cnt, 0, NB * 4, stream);
    slot_kernel<<<(N_OBS + 255) / 256, 256, 0, stream>>>(li, cnt, dst);

    wtrans<<<dim3(256, 3), 256, 0, stream>>>(mlp_w, mlpT, 256, 256);
    pack_w<<<dim3(256, 8), 256, 0, stream>>>(wq, Wqp, 256, 256);
    pack_w<<<dim3(256, 8), 256, 0, stream>>>(wk, Wkp, 256, 256);
    pack_w<<<dim3(256, 8), 256, 0, stream>>>(wv, Wvp, 256, 256);
    pack_w<<<dim3(256, 8), 256, 0, stream>>>(wo, Wop, 256, 256);
    pack_w<<<dim3(1024, 8), 256, 0, stream>>>(w1, W1p, 256, 1024);
    pack_w<<<dim3(1024, 8), 256, 0, stream>>>(w2, W2p, 1024, 256);
    wtrans<<<dim3(4096, 1), 256, 0, stream>>>(pw, pwT, 2048, 512);

    convx<<<18016, 256, 0, stream>>>(x, tmpA);

    dim3 blk(256), g2(MT, 2);
    // MLP: fc1+gelu, fc2+gelu, fc3 -> ctx packed in A-fragment order
    gemm_bt<true, 0><<<g2, blk, 0, stream>>>(tmpA, 256, mlpT, 256, mlp_b,
        tmpB, nullptr, 256, nullptr, 0, 256, 0);
    gemm_bt<true, 0><<<g2, blk, 0, stream>>>(tmpB, 256, mlpT + 65536, 256, mlp_b + 256,
        tmpA, nullptr, 256, nullptr, 0, 256, 0);
    gemm_bt<false, 3><<<g2, blk, 0, stream>>>(tmpA, 256, mlpT + 131072, 256, mlp_b + 512,
        ctxp, nullptr, 256, dst, N_OBS, 256, 0);

    // fused transformer: 750 blocks x 96 rows (exactly 72000 rows), 7 waves each
    fused_tr<<<750, 448, 0, stream>>>(ctxp, Wqp, Wkp, Wvp, Wop, W1p, W2p,
        bg, ln1_g, ln1_b, bq, bk, bv, bo, ln2_g, ln2_b, b1, b2, trb);

    // final projection: [9000,2048] @ [2048,512] -> d_out (fp32)
    gemm_bt<false, 2><<<dim3(71, 4), blk, 0, stream>>>(trb, 2048, pwT, 2048, pb,
        nullptr, (float*)d_out, 512, nullptr, 0, 2048, NB);
}